// Round 1
// baseline (1292.733 us; speedup 1.0000x reference)
//
#include <hip/hip_runtime.h>
#include <cmath>

// EstimatorQNNGen275: conv+sigmoid+mean -> 1-dim attention -> 4-layer tanh MLP
// (3x 512x4096x4096 GEMMs via fp16 MFMA) -> pairwise-fidelity graph weights.
//
// ws layout (bytes):
//   [0,2048)        c_buf   (512 f32)
//   [2048,4096)     attn    (512 f32)
//   [4096,4160)     D       (16 f32, fid dot accumulators, memset 0)
//   [8192, +8MB)    act1    (512*4096 f32)
//   ... act2, act3 follow. act4 = d_out[0:2M). total ~25.2 MB.

#define NEL (512 * 4096)

typedef float  floatx4 __attribute__((ext_vector_type(4)));
typedef _Float16 halfx8 __attribute__((ext_vector_type(8)));
typedef _Float16 halfx4 __attribute__((ext_vector_type(4)));

// ---------------- conv + sigmoid + mean ----------------
__global__ __launch_bounds__(256) void conv_mean_kernel(
    const float* __restrict__ x, const float* __restrict__ cw,
    const float* __restrict__ cb, float* __restrict__ c_out)
{
  __shared__ float sbuf[4];
  const int b = blockIdx.x;
  const float w00 = cw[0], w01 = cw[1], w10 = cw[2], w11 = cw[3];
  const float bias = cb[0];
  const float* xb = x + (size_t)b * 128 * 128;
  float acc = 0.f;
  for (int idx = threadIdx.x; idx < 127 * 127; idx += 256) {
    int i = idx / 127;
    int j = idx - i * 127;
    const float* p = xb + i * 128 + j;
    float v = w00 * p[0] + w01 * p[1] + w10 * p[128] + w11 * p[129] + bias;
    acc += 1.0f / (1.0f + __expf(-v));
  }
  #pragma unroll
  for (int off = 32; off > 0; off >>= 1) acc += __shfl_down(acc, off, 64);
  const int lane = threadIdx.x & 63, wv = threadIdx.x >> 6;
  if (lane == 0) sbuf[wv] = acc;
  __syncthreads();
  if (threadIdx.x == 0)
    c_out[b] = (sbuf[0] + sbuf[1] + sbuf[2] + sbuf[3]) * (1.0f / 16129.0f);
}

// ---------------- 1-dim attention ----------------
// scores[i,j] = softmax_j( (r*e*c_i) * c_j );  attn[i] = sum_j scores[i,j]*c_j
__global__ __launch_bounds__(64) void attn_kernel(
    const float* __restrict__ c, const float* __restrict__ rot,
    const float* __restrict__ ent, float* __restrict__ attn)
{
  const int i = blockIdx.x;
  const int lane = threadIdx.x;
  const float t = rot[0] * ent[0] * c[i];
  float vals[8], cj[8];
  float mx = -1e30f;
  #pragma unroll
  for (int u = 0; u < 8; ++u) {
    float cv = c[lane + u * 64];
    cj[u] = cv;
    vals[u] = t * cv;
    mx = fmaxf(mx, vals[u]);
  }
  #pragma unroll
  for (int off = 32; off > 0; off >>= 1) mx = fmaxf(mx, __shfl_down(mx, off, 64));
  mx = __shfl(mx, 0, 64);
  float se = 0.f, sw = 0.f;
  #pragma unroll
  for (int u = 0; u < 8; ++u) {
    float e = __expf(vals[u] - mx);
    se += e;
    sw += e * cj[u];
  }
  #pragma unroll
  for (int off = 32; off > 0; off >>= 1) {
    se += __shfl_down(se, off, 64);
    sw += __shfl_down(sw, off, 64);
  }
  if (lane == 0) attn[i] = sw / se;
}

// ---------------- layer 1 (outer product + tanh) ----------------
__global__ __launch_bounds__(256) void layer1_kernel(
    const float* __restrict__ attn, const float* __restrict__ W1,
    const float* __restrict__ b1, float* __restrict__ act1)
{
  const int o = blockIdx.x * 256 + threadIdx.x;
  const int i = blockIdx.y;
  act1[(size_t)i * 4096 + o] = tanhf(attn[i] * W1[o] + b1[o]);
}

// ---------------- fp16-MFMA GEMM: C = tanh(A @ W^T + b) ----------------
// A: M x K fp32 row-major (M=512), W: N x K fp32 row-major (4096x4096).
// 128x128 tile, BK=32, 256 thr = 4 waves (2x2), wave = 64x64 = 4x4 mfma tiles.
#define BM 128
#define BN 128
#define BK 32
#define LDK 40  // padded leading dim (halfs): 80B row stride -> 2-way bank alias (free)

__global__ __launch_bounds__(256) void gemm_tanh_kernel(
    const float* __restrict__ A, const float* __restrict__ W,
    const float* __restrict__ bias, float* __restrict__ C)
{
  __shared__ _Float16 As[BM][LDK];
  __shared__ _Float16 Ws[BN][LDK];
  const int K = 4096, N = 4096;
  const int tid  = threadIdx.x;
  const int lane = tid & 63;
  const int wave = tid >> 6;
  const int wm = (wave >> 1) * 64;  // wave row offset in tile
  const int wn = (wave & 1) * 64;   // wave col offset in tile
  const int q  = lane >> 4;         // 0..3 (k-quad / row-quad)
  const int ml = lane & 15;
  const int tileM = blockIdx.y * BM;
  const int tileN = blockIdx.x * BN;

  floatx4 acc[4][4] = {};

  for (int k0 = 0; k0 < K; k0 += BK) {
    __syncthreads();
    // stage 128x32 fp32 -> fp16 LDS for A and W (4 float4 each per thread)
    #pragma unroll
    for (int u = 0; u < 4; ++u) {
      const int id = tid + u * 256;       // 0..1023
      const int r  = id >> 3;             // row 0..127
      const int cc = (id & 7) << 2;       // col 0,4,...,28
      const float4 av = *reinterpret_cast<const float4*>(
          A + (size_t)(tileM + r) * K + k0 + cc);
      halfx4 ha = { (_Float16)av.x, (_Float16)av.y, (_Float16)av.z, (_Float16)av.w };
      *reinterpret_cast<halfx4*>(&As[r][cc]) = ha;
      const float4 wvv = *reinterpret_cast<const float4*>(
          W + (size_t)(tileN + r) * K + k0 + cc);
      halfx4 hw = { (_Float16)wvv.x, (_Float16)wvv.y, (_Float16)wvv.z, (_Float16)wvv.w };
      *reinterpret_cast<halfx4*>(&Ws[r][cc]) = hw;
    }
    __syncthreads();

    halfx8 af[4], bf[4];
    #pragma unroll
    for (int i = 0; i < 4; ++i)
      af[i] = *reinterpret_cast<const halfx8*>(&As[wm + i * 16 + ml][q * 8]);
    #pragma unroll
    for (int j = 0; j < 4; ++j)
      bf[j] = *reinterpret_cast<const halfx8*>(&Ws[wn + j * 16 + ml][q * 8]);

    #pragma unroll
    for (int i = 0; i < 4; ++i)
      #pragma unroll
      for (int j = 0; j < 4; ++j)
        acc[i][j] = __builtin_amdgcn_mfma_f32_16x16x32_f16(af[i], bf[j], acc[i][j], 0, 0, 0);
  }

  // epilogue: C/D layout col=lane&15, row=(lane>>4)*4+reg
  #pragma unroll
  for (int i = 0; i < 4; ++i) {
    const int row0 = tileM + wm + i * 16 + q * 4;
    #pragma unroll
    for (int j = 0; j < 4; ++j) {
      const int col = tileN + wn + j * 16 + ml;
      const float bv = bias[col];
      #pragma unroll
      for (int r = 0; r < 4; ++r)
        C[(size_t)(row0 + r) * N + col] = tanhf(acc[i][j][r] + bv);
    }
  }
}

// ---------------- fid pairwise dots ----------------
__global__ __launch_bounds__(256) void fid_dots_kernel(
    const float* __restrict__ a1, const float* __restrict__ a2,
    const float* __restrict__ a3, const float* __restrict__ a4,
    float* __restrict__ D)
{
  float s[10] = {0, 0, 0, 0, 0, 0, 0, 0, 0, 0};
  const int stride = gridDim.x * blockDim.x;
  for (int idx = blockIdx.x * blockDim.x + threadIdx.x; idx < NEL; idx += stride) {
    float v1 = a1[idx], v2 = a2[idx], v3 = a3[idx], v4 = a4[idx];
    s[0] += v1 * v1; s[1] += v1 * v2; s[2] += v1 * v3; s[3] += v1 * v4;
    s[4] += v2 * v2; s[5] += v2 * v3; s[6] += v2 * v4;
    s[7] += v3 * v3; s[8] += v3 * v4; s[9] += v4 * v4;
  }
  #pragma unroll
  for (int p = 0; p < 10; ++p) {
    float v = s[p];
    #pragma unroll
    for (int off = 32; off > 0; off >>= 1) v += __shfl_down(v, off, 64);
    if ((threadIdx.x & 63) == 0) atomicAdd(&D[p], v);
  }
}

// ---------------- finalize graph weights ----------------
__global__ void finalize_kernel(const float* __restrict__ D, float* __restrict__ wout)
{
  const int i = threadIdx.x;
  if (i >= 16) return;
  const int p = i >> 2, qq = i & 3;
  const int a = p < qq ? p : qq;
  const int b = p < qq ? qq : p;
  const int base[4] = {0, 4, 7, 9};  // index of (a,a) in s[] ordering
  const float dpq = D[base[a] + (b - a)];
  const float npv = sqrtf(D[base[p]]) + 1e-12f;
  const float nqv = sqrtf(D[base[qq]]) + 1e-12f;
  const float ch = dpq / (npv * nqv);
  const float fid = ch * ch;
  wout[i] = (fid >= 0.8f && p != qq) ? 1.0f : 0.0f;
}

extern "C" void kernel_launch(void* const* d_in, const int* in_sizes, int n_in,
                              void* d_out, int out_size, void* d_ws, size_t ws_size,
                              hipStream_t stream)
{
  const float* x   = (const float*)d_in[0];
  const float* cw  = (const float*)d_in[1];
  const float* cb  = (const float*)d_in[2];
  const float* rot = (const float*)d_in[3];
  const float* ent = (const float*)d_in[4];
  const float* W1  = (const float*)d_in[5];
  const float* b1  = (const float*)d_in[6];
  const float* W2  = (const float*)d_in[7];
  const float* b2  = (const float*)d_in[8];
  const float* W3  = (const float*)d_in[9];
  const float* b3  = (const float*)d_in[10];
  const float* W4  = (const float*)d_in[11];
  const float* b4  = (const float*)d_in[12];
  float* out = (float*)d_out;

  char*  ws    = (char*)d_ws;
  float* c_buf = (float*)(ws + 0);
  float* attn  = (float*)(ws + 2048);
  float* D     = (float*)(ws + 4096);
  float* act1  = (float*)(ws + 8192);
  float* act2  = act1 + NEL;
  float* act3  = act2 + NEL;
  float* wout  = out + NEL;

  hipMemsetAsync(D, 0, 16 * sizeof(float), stream);
  conv_mean_kernel<<<512, 256, 0, stream>>>(x, cw, cb, c_buf);
  attn_kernel<<<512, 64, 0, stream>>>(c_buf, rot, ent, attn);
  layer1_kernel<<<dim3(16, 512), 256, 0, stream>>>(attn, W1, b1, act1);
  dim3 ggrid(4096 / BN, 512 / BM);  // (32, 4) = 128 blocks
  gemm_tanh_kernel<<<ggrid, 256, 0, stream>>>(act1, W2, b2, act2);
  gemm_tanh_kernel<<<ggrid, 256, 0, stream>>>(act2, W3, b3, act3);
  gemm_tanh_kernel<<<ggrid, 256, 0, stream>>>(act3, W4, b4, out);
  fid_dots_kernel<<<1024, 256, 0, stream>>>(act1, act2, act3, out, D);
  finalize_kernel<<<1, 64, 0, stream>>>(D, wout);
}

// Round 2
// 429.140 us; speedup vs baseline: 3.0124x; 3.0124x over previous
//
#include <hip/hip_runtime.h>
#include <cmath>

// EstimatorQNNGen275: conv+sigmoid+mean -> 1-dim attention -> 4-layer tanh MLP
// (3x 512x4096x4096 GEMMs via fp16 MFMA, split-K=4) -> pairwise-fidelity graph.
//
// ws layout (bytes):
//   [0,2048)     c_buf (512 f32)
//   [2048,4096)  attn  (512 f32)
//   [4096,4736)  D     (10 dot accumulators, line-padded stride 16 f32)
//   [8192,+8MB)  act1 ; act2 ; act3 ; part (4 x 8MB split-K partials)

#define NEL (512 * 4096)

typedef float  floatx4 __attribute__((ext_vector_type(4)));
typedef _Float16 halfx8 __attribute__((ext_vector_type(8)));
typedef _Float16 halfx4 __attribute__((ext_vector_type(4)));

// ---------------- conv + sigmoid + mean ----------------
__global__ __launch_bounds__(256) void conv_mean_kernel(
    const float* __restrict__ x, const float* __restrict__ cw,
    const float* __restrict__ cb, float* __restrict__ c_out)
{
  __shared__ float sbuf[4];
  const int b = blockIdx.x;
  const float w00 = cw[0], w01 = cw[1], w10 = cw[2], w11 = cw[3];
  const float bias = cb[0];
  const float* xb = x + (size_t)b * 128 * 128;
  float acc = 0.f;
  for (int idx = threadIdx.x; idx < 127 * 127; idx += 256) {
    int i = idx / 127;
    int j = idx - i * 127;
    const float* p = xb + i * 128 + j;
    float v = w00 * p[0] + w01 * p[1] + w10 * p[128] + w11 * p[129] + bias;
    acc += 1.0f / (1.0f + __expf(-v));
  }
  #pragma unroll
  for (int off = 32; off > 0; off >>= 1) acc += __shfl_down(acc, off, 64);
  const int lane = threadIdx.x & 63, wv = threadIdx.x >> 6;
  if (lane == 0) sbuf[wv] = acc;
  __syncthreads();
  if (threadIdx.x == 0)
    c_out[b] = (sbuf[0] + sbuf[1] + sbuf[2] + sbuf[3]) * (1.0f / 16129.0f);
}

// ---------------- 1-dim attention ----------------
__global__ __launch_bounds__(64) void attn_kernel(
    const float* __restrict__ c, const float* __restrict__ rot,
    const float* __restrict__ ent, float* __restrict__ attn)
{
  const int i = blockIdx.x;
  const int lane = threadIdx.x;
  const float t = rot[0] * ent[0] * c[i];
  float vals[8], cj[8];
  float mx = -1e30f;
  #pragma unroll
  for (int u = 0; u < 8; ++u) {
    float cv = c[lane + u * 64];
    cj[u] = cv;
    vals[u] = t * cv;
    mx = fmaxf(mx, vals[u]);
  }
  #pragma unroll
  for (int off = 32; off > 0; off >>= 1) mx = fmaxf(mx, __shfl_down(mx, off, 64));
  mx = __shfl(mx, 0, 64);
  float se = 0.f, sw = 0.f;
  #pragma unroll
  for (int u = 0; u < 8; ++u) {
    float e = __expf(vals[u] - mx);
    se += e;
    sw += e * cj[u];
  }
  #pragma unroll
  for (int off = 32; off > 0; off >>= 1) {
    se += __shfl_down(se, off, 64);
    sw += __shfl_down(sw, off, 64);
  }
  if (lane == 0) attn[i] = sw / se;
}

// ---------------- layer 1 (outer product + tanh) ----------------
__global__ __launch_bounds__(256) void layer1_kernel(
    const float* __restrict__ attn, const float* __restrict__ W1,
    const float* __restrict__ b1, float* __restrict__ act1)
{
  const int o = blockIdx.x * 256 + threadIdx.x;
  const int i = blockIdx.y;
  act1[(size_t)i * 4096 + o] = tanhf(attn[i] * W1[o] + b1[o]);
}

// ---------------- fp16-MFMA GEMM (split-K capable) ----------------
// A: M x K fp32 row-major (M=512), W: N x K fp32 row-major (4096x4096).
// 128x128 tile, BK=32, 256 thr = 4 waves (2x2), wave = 64x64 = 4x4 mfma tiles.
// FUSE=true: full-K, epilogue bias+tanh -> C.
// FUSE=false: K-slice per blockIdx.z, raw fp32 partial -> C + z*NEL.
#define BM 128
#define BN 128
#define BK 32
#define LDK 40  // padded leading dim (halfs): 80B stride -> 2-way bank alias (free)

template<bool FUSE>
__global__ __launch_bounds__(256) void gemm_tanh_kernel(
    const float* __restrict__ A, const float* __restrict__ W,
    const float* __restrict__ bias, float* __restrict__ C)
{
  __shared__ _Float16 As[BM][LDK];
  __shared__ _Float16 Ws[BN][LDK];
  const int K = 4096, N = 4096;
  const int tid  = threadIdx.x;
  const int lane = tid & 63;
  const int wave = tid >> 6;
  const int wm = (wave >> 1) * 64;
  const int wn = (wave & 1) * 64;
  const int q  = lane >> 4;
  const int ml = lane & 15;
  const int tileM = blockIdx.y * BM;
  const int tileN = blockIdx.x * BN;
  const int Kslice = K / gridDim.z;
  const int kbeg = blockIdx.z * Kslice;
  float* Cb = FUSE ? C : C + (size_t)blockIdx.z * NEL;

  floatx4 acc[4][4] = {};

  for (int k0 = kbeg; k0 < kbeg + Kslice; k0 += BK) {
    __syncthreads();
    #pragma unroll
    for (int u = 0; u < 4; ++u) {
      const int id = tid + u * 256;       // 0..1023
      const int r  = id >> 3;             // row 0..127
      const int cc = (id & 7) << 2;       // col 0,4,...,28
      const float4 av = *reinterpret_cast<const float4*>(
          A + (size_t)(tileM + r) * K + k0 + cc);
      halfx4 ha = { (_Float16)av.x, (_Float16)av.y, (_Float16)av.z, (_Float16)av.w };
      *reinterpret_cast<halfx4*>(&As[r][cc]) = ha;
      const float4 wvv = *reinterpret_cast<const float4*>(
          W + (size_t)(tileN + r) * K + k0 + cc);
      halfx4 hw = { (_Float16)wvv.x, (_Float16)wvv.y, (_Float16)wvv.z, (_Float16)wvv.w };
      *reinterpret_cast<halfx4*>(&Ws[r][cc]) = hw;
    }
    __syncthreads();

    halfx8 af[4], bf[4];
    #pragma unroll
    for (int i = 0; i < 4; ++i)
      af[i] = *reinterpret_cast<const halfx8*>(&As[wm + i * 16 + ml][q * 8]);
    #pragma unroll
    for (int j = 0; j < 4; ++j)
      bf[j] = *reinterpret_cast<const halfx8*>(&Ws[wn + j * 16 + ml][q * 8]);

    #pragma unroll
    for (int i = 0; i < 4; ++i)
      #pragma unroll
      for (int j = 0; j < 4; ++j)
        acc[i][j] = __builtin_amdgcn_mfma_f32_16x16x32_f16(af[i], bf[j], acc[i][j], 0, 0, 0);
  }

  // C/D layout: col=lane&15, row=(lane>>4)*4+reg
  #pragma unroll
  for (int i = 0; i < 4; ++i) {
    const int row0 = tileM + wm + i * 16 + q * 4;
    #pragma unroll
    for (int j = 0; j < 4; ++j) {
      const int col = tileN + wn + j * 16 + ml;
      if (FUSE) {
        const float bv = bias[col];
        #pragma unroll
        for (int r = 0; r < 4; ++r)
          Cb[(size_t)(row0 + r) * N + col] = tanhf(acc[i][j][r] + bv);
      } else {
        #pragma unroll
        for (int r = 0; r < 4; ++r)
          Cb[(size_t)(row0 + r) * N + col] = acc[i][j][r];
      }
    }
  }
}

// ---------------- split-K combine: sum 4 slices + bias + tanh ----------------
__global__ __launch_bounds__(256) void combine_tanh_kernel(
    const float* __restrict__ part, const float* __restrict__ bias,
    float* __restrict__ outp)
{
  const int i4 = blockIdx.x * 256 + threadIdx.x;  // < NEL/4
  const floatx4* p4 = (const floatx4*)part;
  floatx4 s = p4[i4] + p4[NEL / 4 + i4] + p4[2 * (NEL / 4) + i4] + p4[3 * (NEL / 4) + i4];
  const floatx4 bv = ((const floatx4*)bias)[i4 & 1023];
  floatx4 o;
  #pragma unroll
  for (int r = 0; r < 4; ++r) o[r] = tanhf(s[r] + bv[r]);
  ((floatx4*)outp)[i4] = o;
}

// ---------------- fid pairwise dots (low-contention) ----------------
// D slots line-padded: counter p lives at D[p*16] (64B apart).
__global__ __launch_bounds__(256) void fid_dots_kernel(
    const float* __restrict__ a1, const float* __restrict__ a2,
    const float* __restrict__ a3, const float* __restrict__ a4,
    float* __restrict__ D)
{
  __shared__ float sred[4][10];
  float s[10] = {0, 0, 0, 0, 0, 0, 0, 0, 0, 0};
  const int n4 = NEL / 4;
  const int stride = gridDim.x * blockDim.x;
  const floatx4* p1 = (const floatx4*)a1;
  const floatx4* p2 = (const floatx4*)a2;
  const floatx4* p3 = (const floatx4*)a3;
  const floatx4* p4 = (const floatx4*)a4;
  for (int i = blockIdx.x * 256 + threadIdx.x; i < n4; i += stride) {
    floatx4 v1 = p1[i], v2 = p2[i], v3 = p3[i], v4 = p4[i];
    #pragma unroll
    for (int r = 0; r < 4; ++r) {
      s[0] += v1[r] * v1[r]; s[1] += v1[r] * v2[r]; s[2] += v1[r] * v3[r];
      s[3] += v1[r] * v4[r]; s[4] += v2[r] * v2[r]; s[5] += v2[r] * v3[r];
      s[6] += v2[r] * v4[r]; s[7] += v3[r] * v3[r]; s[8] += v3[r] * v4[r];
      s[9] += v4[r] * v4[r];
    }
  }
  const int lane = threadIdx.x & 63, wv = threadIdx.x >> 6;
  #pragma unroll
  for (int p = 0; p < 10; ++p) {
    float v = s[p];
    #pragma unroll
    for (int off = 32; off > 0; off >>= 1) v += __shfl_down(v, off, 64);
    if (lane == 0) sred[wv][p] = v;
  }
  __syncthreads();
  if (threadIdx.x < 10) {
    float v = sred[0][threadIdx.x] + sred[1][threadIdx.x] +
              sred[2][threadIdx.x] + sred[3][threadIdx.x];
    atomicAdd(&D[threadIdx.x * 16], v);
  }
}

// ---------------- finalize graph weights ----------------
__global__ void finalize_kernel(const float* __restrict__ D, float* __restrict__ wout)
{
  const int i = threadIdx.x;
  if (i >= 16) return;
  const int p = i >> 2, qq = i & 3;
  const int a = p < qq ? p : qq;
  const int b = p < qq ? qq : p;
  const int base[4] = {0, 4, 7, 9};
  const float dpq = D[(base[a] + (b - a)) * 16];
  const float npv = sqrtf(D[base[p] * 16]) + 1e-12f;
  const float nqv = sqrtf(D[base[qq] * 16]) + 1e-12f;
  const float ch = dpq / (npv * nqv);
  const float fid = ch * ch;
  wout[i] = (fid >= 0.8f && p != qq) ? 1.0f : 0.0f;
}

extern "C" void kernel_launch(void* const* d_in, const int* in_sizes, int n_in,
                              void* d_out, int out_size, void* d_ws, size_t ws_size,
                              hipStream_t stream)
{
  const float* x   = (const float*)d_in[0];
  const float* cw  = (const float*)d_in[1];
  const float* cb  = (const float*)d_in[2];
  const float* rot = (const float*)d_in[3];
  const float* ent = (const float*)d_in[4];
  const float* W1  = (const float*)d_in[5];
  const float* b1  = (const float*)d_in[6];
  const float* W2  = (const float*)d_in[7];
  const float* b2  = (const float*)d_in[8];
  const float* W3  = (const float*)d_in[9];
  const float* b3  = (const float*)d_in[10];
  const float* W4  = (const float*)d_in[11];
  const float* b4  = (const float*)d_in[12];
  float* out = (float*)d_out;

  char*  ws    = (char*)d_ws;
  float* c_buf = (float*)(ws + 0);
  float* attn  = (float*)(ws + 2048);
  float* D     = (float*)(ws + 4096);
  float* act1  = (float*)(ws + 8192);
  float* act2  = act1 + NEL;
  float* act3  = act2 + NEL;
  float* part  = act3 + NEL;  // 4 x NEL fp32 split-K partials
  float* wout  = out + NEL;

  const size_t need = 8192 + (size_t)3 * NEL * 4 + (size_t)4 * NEL * 4;
  const bool splitk = ws_size >= need;

  hipMemsetAsync(D, 0, 10 * 16 * sizeof(float), stream);
  conv_mean_kernel<<<512, 256, 0, stream>>>(x, cw, cb, c_buf);
  attn_kernel<<<512, 64, 0, stream>>>(c_buf, rot, ent, attn);
  layer1_kernel<<<dim3(16, 512), 256, 0, stream>>>(attn, W1, b1, act1);

  if (splitk) {
    dim3 g(4096 / BN, 512 / BM, 4);  // 512 blocks -> 2 blocks/CU
    const int cgrid = NEL / 4 / 256;
    gemm_tanh_kernel<false><<<g, 256, 0, stream>>>(act1, W2, nullptr, part);
    combine_tanh_kernel<<<cgrid, 256, 0, stream>>>(part, b2, act2);
    gemm_tanh_kernel<false><<<g, 256, 0, stream>>>(act2, W3, nullptr, part);
    combine_tanh_kernel<<<cgrid, 256, 0, stream>>>(part, b3, act3);
    gemm_tanh_kernel<false><<<g, 256, 0, stream>>>(act3, W4, nullptr, part);
    combine_tanh_kernel<<<cgrid, 256, 0, stream>>>(part, b4, out);
  } else {
    dim3 g(4096 / BN, 512 / BM, 1);
    gemm_tanh_kernel<true><<<g, 256, 0, stream>>>(act1, W2, b2, act2);
    gemm_tanh_kernel<true><<<g, 256, 0, stream>>>(act2, W3, b3, act3);
    gemm_tanh_kernel<true><<<g, 256, 0, stream>>>(act3, W4, b4, out);
  }

  fid_dots_kernel<<<256, 256, 0, stream>>>(act1, act2, act3, out, D);
  finalize_kernel<<<1, 64, 0, stream>>>(D, wout);
}